// Round 1
// baseline (6618.361 us; speedup 1.0000x reference)
//
#include <hip/hip_runtime.h>
#include <hip/hip_bf16.h>
#include <stdint.h>

// Sparse autoencoder: z1 = x@W^T + b_enc ; top-k(3276) mask ; z2 = a1@W + b_dec
// x[4096,4096] f32, W[32768,4096] f32, out z2[4096,4096] f32.

#define DIM      4096
#define BATCH    4096
#define NROWS_W  32768
#define KCNT     3276

typedef __bf16 bf16x8 __attribute__((ext_vector_type(8)));
typedef __bf16 bf16x4 __attribute__((ext_vector_type(4)));
typedef float  f32x4  __attribute__((ext_vector_type(4)));

__device__ __forceinline__ void gload_lds16(const void* g, void* l) {
  __builtin_amdgcn_global_load_lds(
      (const __attribute__((address_space(1))) void*)g,
      (__attribute__((address_space(3))) void*)l, 16, 0, 0);
}

// ---------------- split fp32 -> bf16 hi + bf16 lo ----------------
__global__ void k_split(const float* __restrict__ s, __bf16* __restrict__ hi,
                        __bf16* __restrict__ lo, int n4) {
  int i = blockIdx.x * 256 + threadIdx.x;
  const int stride = gridDim.x * 256;
  for (; i < n4; i += stride) {
    f32x4 v = ((const f32x4*)s)[i];
    bf16x4 h, l;
#pragma unroll
    for (int j = 0; j < 4; ++j) {
      __bf16 hb = (__bf16)v[j];
      h[j] = hb;
      l[j] = (__bf16)(v[j] - (float)hb);
    }
    ((bf16x4*)hi)[i] = h;
    ((bf16x4*)lo)[i] = l;
  }
}

// ---------------- bf16 transpose (tiled) ----------------
__global__ void k_transpose(const __bf16* __restrict__ src, __bf16* __restrict__ dst,
                            int R, int C) {
  __shared__ __bf16 t[32][33];
  const int c0 = blockIdx.x * 32, r0 = blockIdx.y * 32;
  for (int rr = threadIdx.y; rr < 32; rr += 8)
    t[rr][threadIdx.x] = src[(long)(r0 + rr) * C + c0 + threadIdx.x];
  __syncthreads();
  for (int rr = threadIdx.y; rr < 32; rr += 8)
    dst[(long)(c0 + rr) * R + r0 + threadIdx.x] = t[threadIdx.x][rr];
}

// ---------------- GEMM: C[M,N] = A[M,K] * B^T[N,K] + bias, fp32 out ----------------
// SPLIT=1: A,B have lo parts; acc += Ah*Bh + Ah*Bl + Al*Bh  (near-fp32 precision)
template <int SPLIT>
__global__ __launch_bounds__(256, 2)
void k_gemm(const __bf16* __restrict__ A, const __bf16* __restrict__ Al,
            const __bf16* __restrict__ B, const __bf16* __restrict__ Bl,
            const float* __restrict__ bias, float* __restrict__ C,
            int M, int N, int Kt) {
  constexpr int BM = 128, BN = 128, BK = 64;
  __shared__ __align__(16) __bf16 sA[BM * BK];
  __shared__ __align__(16) __bf16 sB[BN * BK];
  __shared__ __align__(16) __bf16 sAl[SPLIT ? BM * BK : 8];
  __shared__ __align__(16) __bf16 sBl[SPLIT ? BN * BK : 8];

  const int tid = threadIdx.x;
  const int nbn = N / BN;
  const int bm = blockIdx.x / nbn, bn = blockIdx.x % nbn;
  const int m0 = bm * BM, n0 = bn * BN;
  const int lane = tid & 63, wid = tid >> 6;
  const int wm = wid >> 1, wn = wid & 1;
  const int lr = lane & 15, lk = lane >> 4;

  f32x4 acc[4][4] = {};

  for (int k0 = 0; k0 < Kt; k0 += BK) {
#pragma unroll
    for (int r = 0; r < 4; ++r) {
      const int o = (r * 256 + tid) * 16;  // byte offset into 16KB tile
      const int row = o >> 7;              // 128 B per tile row (64 bf16)
      const int colb = o & 127;
      const long gA = ((long)(m0 + row) * Kt + k0) * 2 + colb;
      const long gB = ((long)(n0 + row) * Kt + k0) * 2 + colb;
      gload_lds16((const char*)A + gA, (char*)sA + o);
      gload_lds16((const char*)B + gB, (char*)sB + o);
      if (SPLIT) {
        gload_lds16((const char*)Al + gA, (char*)sAl + o);
        gload_lds16((const char*)Bl + gB, (char*)sBl + o);
      }
    }
    __syncthreads();  // compiler drains vmcnt before s_barrier

#pragma unroll
    for (int kk = 0; kk < 2; ++kk) {
      bf16x8 va[4], vb[4], wa[4], wb[4];
      const int kof = kk * 32 + lk * 8;
#pragma unroll
      for (int m = 0; m < 4; ++m) {
        const int row = wm * 64 + m * 16 + lr;
        va[m] = *(const bf16x8*)&sA[row * BK + kof];
        if (SPLIT) wa[m] = *(const bf16x8*)&sAl[row * BK + kof];
      }
#pragma unroll
      for (int n = 0; n < 4; ++n) {
        const int row = wn * 64 + n * 16 + lr;
        vb[n] = *(const bf16x8*)&sB[row * BK + kof];
        if (SPLIT) wb[n] = *(const bf16x8*)&sBl[row * BK + kof];
      }
#pragma unroll
      for (int m = 0; m < 4; ++m)
#pragma unroll
        for (int n = 0; n < 4; ++n) {
          acc[m][n] = __builtin_amdgcn_mfma_f32_16x16x32_bf16(va[m], vb[n], acc[m][n], 0, 0, 0);
          if (SPLIT) {
            acc[m][n] = __builtin_amdgcn_mfma_f32_16x16x32_bf16(va[m], wb[n], acc[m][n], 0, 0, 0);
            acc[m][n] = __builtin_amdgcn_mfma_f32_16x16x32_bf16(wa[m], vb[n], acc[m][n], 0, 0, 0);
          }
        }
    }
    __syncthreads();
  }

  // C/D layout: col = lane&15, row = (lane>>4)*4 + reg
#pragma unroll
  for (int n = 0; n < 4; ++n) {
    const int col = n0 + wn * 64 + n * 16 + lr;
    const float bv = bias[col];
#pragma unroll
    for (int m = 0; m < 4; ++m) {
      const int r0r = m0 + wm * 64 + m * 16 + lk * 4;
#pragma unroll
      for (int j = 0; j < 4; ++j)
        C[(long)(r0r + j) * N + col] = acc[m][n][j] + bv;
    }
  }
}

// ---------------- per-row k-th largest via 4-level radix select ----------------
__device__ __forceinline__ unsigned f2o(float f) {
  unsigned b = __float_as_uint(f);
  return ((int)b < 0) ? ~b : (b | 0x80000000u);
}
__device__ __forceinline__ float o2f(unsigned u) {
  unsigned b = (u & 0x80000000u) ? (u & 0x7FFFFFFFu) : ~u;
  return __uint_as_float(b);
}

__global__ void k_topk(const float* __restrict__ z1, float* __restrict__ thr,
                       int ncols, int kwant) {
  __shared__ unsigned hist[256];
  __shared__ unsigned s_dig, s_rem;
  const long base = (long)blockIdx.x * ncols;
  unsigned prefix = 0;
  unsigned remaining = (unsigned)kwant;
  for (int level = 0; level < 4; ++level) {
    const int shift = 24 - level * 8;
    hist[threadIdx.x] = 0;  // blockDim.x == 256
    __syncthreads();
    const unsigned pmask = (level == 0) ? 0u : (0xFFFFFFFFu << (shift + 8));
    for (int i = threadIdx.x; i < ncols; i += 256) {
      unsigned u = f2o(z1[base + i]);
      if ((u & pmask) == (prefix & pmask))
        atomicAdd(&hist[(u >> shift) & 255u], 1u);
    }
    __syncthreads();
    if (threadIdx.x == 0) {
      unsigned cum = 0;
      int d = 255;
      for (; d > 0; --d) {
        if (cum + hist[d] >= remaining) break;
        cum += hist[d];
      }
      s_dig = (unsigned)d;
      s_rem = remaining - cum;
    }
    __syncthreads();
    prefix |= (s_dig << shift);
    remaining = s_rem;
    __syncthreads();
  }
  if (threadIdx.x == 0) thr[blockIdx.x] = o2f(prefix);
}

// ---------------- apply mask, write bf16 a1 ----------------
__global__ void k_mask(const float* __restrict__ z1, const float* __restrict__ thr,
                       __bf16* __restrict__ a1, int n4, int ncols4) {
  int i = blockIdx.x * 256 + threadIdx.x;
  const int stride = gridDim.x * 256;
  for (; i < n4; i += stride) {
    f32x4 v = ((const f32x4*)z1)[i];
    const float t = thr[i / ncols4];
    bf16x4 o;
#pragma unroll
    for (int j = 0; j < 4; ++j)
      o[j] = (v[j] >= t) ? (__bf16)v[j] : (__bf16)0.0f;
    ((bf16x4*)a1)[i] = o;
  }
}

extern "C" void kernel_launch(void* const* d_in, const int* in_sizes, int n_in,
                              void* d_out, int out_size, void* d_ws, size_t ws_size,
                              hipStream_t stream) {
  const float* x     = (const float*)d_in[0];
  const float* W     = (const float*)d_in[1];
  const float* b_enc = (const float*)d_in[2];
  const float* b_dec = (const float*)d_in[3];
  // d_in[4] = epoch, unused in eval mode
  float* out = (float*)d_out;

  const long NW = (long)NROWS_W * DIM;    // 134217728
  const long NX = (long)BATCH * DIM;      // 16777216
  const long NZ = (long)BATCH * NROWS_W;  // 134217728

  char* ws = (char*)d_ws;
  __bf16* Wh = (__bf16*)ws;        // 2*NW bytes
  __bf16* Wl = Wh + NW;            // 2*NW
  __bf16* Wt = Wl + NW;            // 2*NW  (W^T hi, [DIM][NROWS_W])
  __bf16* xh = Wt + NW;            // 2*NX
  __bf16* xl = xh + NX;            // 2*NX
  float*  z1 = (float*)(xl + NX);  // 4*NZ
  float*  thr = z1 + NZ;           // 4*BATCH
  __bf16* a1 = Wl;                 // Wl dead after encoder GEMM -> reuse as a1

  const size_t needed = (size_t)(6 * NW + 4 * NX) + (size_t)4 * NZ + 4 * BATCH;
  if (ws_size < needed) return;  // would corrupt; fail visibly instead

  k_split<<<2048, 256, 0, stream>>>(W, Wh, Wl, (int)(NW / 4));
  k_split<<<2048, 256, 0, stream>>>(x, xh, xl, (int)(NX / 4));
  k_transpose<<<dim3(DIM / 32, NROWS_W / 32), dim3(32, 8), 0, stream>>>(Wh, Wt, NROWS_W, DIM);

  // encoder: z1[BATCH, NROWS_W] = x @ W^T (split-bf16, 3 products) + b_enc
  k_gemm<1><<<(BATCH / 128) * (NROWS_W / 128), 256, 0, stream>>>(
      xh, xl, Wh, Wl, b_enc, z1, BATCH, NROWS_W, DIM);

  k_topk<<<BATCH, 256, 0, stream>>>(z1, thr, NROWS_W, KCNT);
  k_mask<<<2048, 256, 0, stream>>>(z1, thr, a1, (int)(NZ / 4), NROWS_W / 4);

  // decoder: out[BATCH, DIM] = a1 @ W + b_dec  (B^T = Wt)
  k_gemm<0><<<(BATCH / 128) * (DIM / 128), 256, 0, stream>>>(
      a1, nullptr, Wt, nullptr, b_dec, out, BATCH, DIM, NROWS_W);
}

// Round 2
// 5399.675 us; speedup vs baseline: 1.2257x; 1.2257x over previous
//
#include <hip/hip_runtime.h>
#include <hip/hip_bf16.h>
#include <stdint.h>

// Sparse autoencoder: z1 = x@W^T + b_enc ; top-k(3276) mask ; z2 = a1@W + b_dec
// x[4096,4096] f32, W[32768,4096] f32, out z2[4096,4096] f32.

#define DIM      4096
#define BATCH    4096
#define NROWS_W  32768
#define KCNT     3276

typedef __bf16 bf16x8 __attribute__((ext_vector_type(8)));
typedef __bf16 bf16x4 __attribute__((ext_vector_type(4)));
typedef float  f32x4  __attribute__((ext_vector_type(4)));

__device__ __forceinline__ void gload_lds16(const void* g, void* l) {
  __builtin_amdgcn_global_load_lds(
      (const __attribute__((address_space(1))) void*)g,
      (__attribute__((address_space(3))) void*)l, 16, 0, 0);
}

// ---------------- split fp32 -> bf16 hi + bf16 lo ----------------
__global__ void k_split(const float* __restrict__ s, __bf16* __restrict__ hi,
                        __bf16* __restrict__ lo, int n4) {
  int i = blockIdx.x * 256 + threadIdx.x;
  const int stride = gridDim.x * 256;
  for (; i < n4; i += stride) {
    f32x4 v = ((const f32x4*)s)[i];
    bf16x4 h, l;
#pragma unroll
    for (int j = 0; j < 4; ++j) {
      __bf16 hb = (__bf16)v[j];
      h[j] = hb;
      l[j] = (__bf16)(v[j] - (float)hb);
    }
    ((bf16x4*)hi)[i] = h;
    ((bf16x4*)lo)[i] = l;
  }
}

// ---------------- bf16 transpose (tiled) ----------------
__global__ void k_transpose(const __bf16* __restrict__ src, __bf16* __restrict__ dst,
                            int R, int C) {
  __shared__ __bf16 t[32][33];
  const int c0 = blockIdx.x * 32, r0 = blockIdx.y * 32;
  for (int rr = threadIdx.y; rr < 32; rr += 8)
    t[rr][threadIdx.x] = src[(long)(r0 + rr) * C + c0 + threadIdx.x];
  __syncthreads();
  for (int rr = threadIdx.y; rr < 32; rr += 8)
    dst[(long)(c0 + rr) * R + r0 + threadIdx.x] = t[threadIdx.x][rr];
}

// ---------------- GEMM: C[M,N] = A[M,K] * B^T[N,K] + bias, fp32 out ----------------
// SPLIT=1: A,B have lo parts; acc += Ah*Bh + Ah*Bl + Al*Bh  (near-fp32 precision)
// LDS tiles use T2 XOR-swizzle: 16B slot within each 128B row is XORed with
// (row&7). Staging pre-swizzles the GLOBAL source (global_load_lds writes
// linearly); ds_read applies the same XOR (rule #21: both-sides-or-neither).
template <int SPLIT>
__global__ __launch_bounds__(256, 2)
void k_gemm(const __bf16* __restrict__ A, const __bf16* __restrict__ Al,
            const __bf16* __restrict__ B, const __bf16* __restrict__ Bl,
            const float* __restrict__ bias, float* __restrict__ C,
            int M, int N, int Kt) {
  constexpr int BM = 128, BN = 128, BK = 64;
  __shared__ __align__(16) __bf16 sA[BM * BK];
  __shared__ __align__(16) __bf16 sB[BN * BK];
  __shared__ __align__(16) __bf16 sAl[SPLIT ? BM * BK : 8];
  __shared__ __align__(16) __bf16 sBl[SPLIT ? BN * BK : 8];

  const int tid = threadIdx.x;
  const int nbn = N / BN;
  const int bm = blockIdx.x / nbn, bn = blockIdx.x % nbn;
  const int m0 = bm * BM, n0 = bn * BN;
  const int lane = tid & 63, wid = tid >> 6;
  const int wm = wid >> 1, wn = wid & 1;
  const int lr = lane & 15, lk = lane >> 4;
  const int swz = (lr & 7) << 4;  // read-side XOR (row&7 == lr&7 for all frags)

  f32x4 acc[4][4] = {};

  for (int k0 = 0; k0 < Kt; k0 += BK) {
#pragma unroll
    for (int r = 0; r < 4; ++r) {
      const int o = (r * 256 + tid) * 16;  // byte offset into 16KB tile
      const int row = o >> 7;              // 128 B per tile row (64 bf16)
      const int colb = (o & 127) ^ ((row & 7) << 4);  // pre-swizzled source
      const long gA = ((long)(m0 + row) * Kt + k0) * 2 + colb;
      const long gB = ((long)(n0 + row) * Kt + k0) * 2 + colb;
      gload_lds16((const char*)A + gA, (char*)sA + o);
      gload_lds16((const char*)B + gB, (char*)sB + o);
      if (SPLIT) {
        gload_lds16((const char*)Al + gA, (char*)sAl + o);
        gload_lds16((const char*)Bl + gB, (char*)sBl + o);
      }
    }
    __syncthreads();  // compiler drains vmcnt before s_barrier

#pragma unroll
    for (int kk = 0; kk < 2; ++kk) {
      bf16x8 va[4], vb[4], wa[4], wb[4];
      const int kbase = (kk * 64 + lk * 16) ^ swz;  // swizzled byte col
#pragma unroll
      for (int m = 0; m < 4; ++m) {
        const int row = wm * 64 + m * 16 + lr;
        va[m] = *(const bf16x8*)((const char*)sA + row * 128 + kbase);
        if (SPLIT) wa[m] = *(const bf16x8*)((const char*)sAl + row * 128 + kbase);
      }
#pragma unroll
      for (int n = 0; n < 4; ++n) {
        const int row = wn * 64 + n * 16 + lr;
        vb[n] = *(const bf16x8*)((const char*)sB + row * 128 + kbase);
        if (SPLIT) wb[n] = *(const bf16x8*)((const char*)sBl + row * 128 + kbase);
      }
#pragma unroll
      for (int m = 0; m < 4; ++m)
#pragma unroll
        for (int n = 0; n < 4; ++n) {
          acc[m][n] = __builtin_amdgcn_mfma_f32_16x16x32_bf16(va[m], vb[n], acc[m][n], 0, 0, 0);
          if (SPLIT) {
            acc[m][n] = __builtin_amdgcn_mfma_f32_16x16x32_bf16(va[m], wb[n], acc[m][n], 0, 0, 0);
            acc[m][n] = __builtin_amdgcn_mfma_f32_16x16x32_bf16(wa[m], vb[n], acc[m][n], 0, 0, 0);
          }
        }
    }
    __syncthreads();
  }

  // C/D layout: col = lane&15, row = (lane>>4)*4 + reg
#pragma unroll
  for (int n = 0; n < 4; ++n) {
    const int col = n0 + wn * 64 + n * 16 + lr;
    const float bv = bias[col];
#pragma unroll
    for (int m = 0; m < 4; ++m) {
      const int r0r = m0 + wm * 64 + m * 16 + lk * 4;
#pragma unroll
      for (int j = 0; j < 4; ++j)
        C[(long)(r0r + j) * N + col] = acc[m][n][j] + bv;
    }
  }
}

// ---------------- per-row k-th largest via 4-level radix select ----------------
__device__ __forceinline__ unsigned f2o(float f) {
  unsigned b = __float_as_uint(f);
  return ((int)b < 0) ? ~b : (b | 0x80000000u);
}
__device__ __forceinline__ float o2f(unsigned u) {
  unsigned b = (u & 0x80000000u) ? (u & 0x7FFFFFFFu) : ~u;
  return __uint_as_float(b);
}

__global__ void k_topk(const float* __restrict__ z1, float* __restrict__ thr,
                       int ncols, int kwant) {
  __shared__ unsigned hist[256];
  __shared__ unsigned s_dig, s_rem;
  const long base = (long)blockIdx.x * ncols;
  unsigned prefix = 0;
  unsigned remaining = (unsigned)kwant;
  for (int level = 0; level < 4; ++level) {
    const int shift = 24 - level * 8;
    hist[threadIdx.x] = 0;  // blockDim.x == 256
    __syncthreads();
    const unsigned pmask = (level == 0) ? 0u : (0xFFFFFFFFu << (shift + 8));
    for (int i = threadIdx.x; i < ncols; i += 256) {
      unsigned u = f2o(z1[base + i]);
      if ((u & pmask) == (prefix & pmask))
        atomicAdd(&hist[(u >> shift) & 255u], 1u);
    }
    __syncthreads();
    if (threadIdx.x == 0) {
      unsigned cum = 0;
      int d = 255;
      for (; d > 0; --d) {
        if (cum + hist[d] >= remaining) break;
        cum += hist[d];
      }
      s_dig = (unsigned)d;
      s_rem = remaining - cum;
    }
    __syncthreads();
    prefix |= (s_dig << shift);
    remaining = s_rem;
    __syncthreads();
  }
  if (threadIdx.x == 0) thr[blockIdx.x] = o2f(prefix);
}

// ---------------- apply mask, write bf16 a1 ----------------
__global__ void k_mask(const float* __restrict__ z1, const float* __restrict__ thr,
                       __bf16* __restrict__ a1, int n4, int ncols4) {
  int i = blockIdx.x * 256 + threadIdx.x;
  const int stride = gridDim.x * 256;
  for (; i < n4; i += stride) {
    f32x4 v = ((const f32x4*)z1)[i];
    const float t = thr[i / ncols4];
    bf16x4 o;
#pragma unroll
    for (int j = 0; j < 4; ++j)
      o[j] = (v[j] >= t) ? (__bf16)v[j] : (__bf16)0.0f;
    ((bf16x4*)a1)[i] = o;
  }
}

extern "C" void kernel_launch(void* const* d_in, const int* in_sizes, int n_in,
                              void* d_out, int out_size, void* d_ws, size_t ws_size,
                              hipStream_t stream) {
  const float* x     = (const float*)d_in[0];
  const float* W     = (const float*)d_in[1];
  const float* b_enc = (const float*)d_in[2];
  const float* b_dec = (const float*)d_in[3];
  // d_in[4] = epoch, unused in eval mode
  float* out = (float*)d_out;

  const long NW = (long)NROWS_W * DIM;    // 134217728
  const long NX = (long)BATCH * DIM;      // 16777216
  const long NZ = (long)BATCH * NROWS_W;  // 134217728

  char* ws = (char*)d_ws;
  __bf16* Wh = (__bf16*)ws;        // 2*NW bytes
  __bf16* Wl = Wh + NW;            // 2*NW
  __bf16* Wt = Wl + NW;            // 2*NW  (W^T hi, [DIM][NROWS_W])
  __bf16* xh = Wt + NW;            // 2*NX
  __bf16* xl = xh + NX;            // 2*NX
  float*  z1 = (float*)(xl + NX);  // 4*NZ
  float*  thr = z1 + NZ;           // 4*BATCH
  __bf16* a1 = Wl;                 // Wl dead after encoder GEMM -> reuse as a1

  const size_t needed = (size_t)(6 * NW + 4 * NX) + (size_t)4 * NZ + 4 * BATCH;
  if (ws_size < needed) return;  // would corrupt; fail visibly instead

  k_split<<<2048, 256, 0, stream>>>(W, Wh, Wl, (int)(NW / 4));
  k_split<<<2048, 256, 0, stream>>>(x, xh, xl, (int)(NX / 4));
  k_transpose<<<dim3(DIM / 32, NROWS_W / 32), dim3(32, 8), 0, stream>>>(Wh, Wt, NROWS_W, DIM);

  // encoder: z1[BATCH, NROWS_W] = x @ W^T (split-bf16, 3 products) + b_enc
  k_gemm<1><<<(BATCH / 128) * (NROWS_W / 128), 256, 0, stream>>>(
      xh, xl, Wh, Wl, b_enc, z1, BATCH, NROWS_W, DIM);

  k_topk<<<BATCH, 256, 0, stream>>>(z1, thr, NROWS_W, KCNT);
  k_mask<<<2048, 256, 0, stream>>>(z1, thr, a1, (int)(NZ / 4), NROWS_W / 4);

  // decoder: out[BATCH, DIM] = a1 @ W + b_dec  (B^T = Wt)
  k_gemm<0><<<(BATCH / 128) * (DIM / 128), 256, 0, stream>>>(
      a1, nullptr, Wt, nullptr, b_dec, out, BATCH, DIM, NROWS_W);
}

// Round 3
// 4601.270 us; speedup vs baseline: 1.4384x; 1.1735x over previous
//
#include <hip/hip_runtime.h>
#include <hip/hip_bf16.h>
#include <stdint.h>

// Sparse autoencoder: z1 = x@W^T + b_enc ; top-k(3276) mask ; z2 = a1@W + b_dec
// x[4096,4096] f32, W[32768,4096] f32, out z2[4096,4096] f32.
// Strategy: encoder = single bf16 MFMA GEMM (approx z1, err sigma ~1.7e-3);
// exact top-k selection restored by recomputing an fp32-exact dot only for
// features within DELTA of the approx threshold (~115/row), h-major so W
// streams once. a1 values use approx z1 (sub-bf16-ulp error).

#define DIM      4096
#define BATCH    4096
#define NROWS_W  32768
#define KCNT     3276
#define DELTA    0.010f
#define ROWCAP   384
#define HCAP     64

typedef __bf16 bf16x8 __attribute__((ext_vector_type(8)));
typedef __bf16 bf16x4 __attribute__((ext_vector_type(4)));
typedef float  f32x4  __attribute__((ext_vector_type(4)));

__device__ __forceinline__ void gload_lds16(const void* g, void* l) {
  __builtin_amdgcn_global_load_lds(
      (const __attribute__((address_space(1))) void*)g,
      (__attribute__((address_space(3))) void*)l, 16, 0, 0);
}

// ---------------- split fp32 -> bf16 hi + bf16 lo ----------------
__global__ void k_split(const float* __restrict__ s, __bf16* __restrict__ hi,
                        __bf16* __restrict__ lo, int n4) {
  int i = blockIdx.x * 256 + threadIdx.x;
  const int stride = gridDim.x * 256;
  for (; i < n4; i += stride) {
    f32x4 v = ((const f32x4*)s)[i];
    bf16x4 h, l;
#pragma unroll
    for (int j = 0; j < 4; ++j) {
      __bf16 hb = (__bf16)v[j];
      h[j] = hb;
      l[j] = (__bf16)(v[j] - (float)hb);
    }
    ((bf16x4*)hi)[i] = h;
    ((bf16x4*)lo)[i] = l;
  }
}

// ---------------- bf16 transpose (tiled) ----------------
__global__ void k_transpose(const __bf16* __restrict__ src, __bf16* __restrict__ dst,
                            int R, int C) {
  __shared__ __bf16 t[32][33];
  const int c0 = blockIdx.x * 32, r0 = blockIdx.y * 32;
  for (int rr = threadIdx.y; rr < 32; rr += 8)
    t[rr][threadIdx.x] = src[(long)(r0 + rr) * C + c0 + threadIdx.x];
  __syncthreads();
  for (int rr = threadIdx.y; rr < 32; rr += 8)
    dst[(long)(c0 + rr) * R + r0 + threadIdx.x] = t[threadIdx.x][rr];
}

// ---------------- GEMM: C[M,N] = A[M,K] * B^T[N,K] + bias, fp32 out ----------------
// T2 XOR-swizzled LDS (pre-swizzled global source + swizzled ds_read).
// Block remap: 16x32 supertiles so resident blocks share A-rows/B-cols (L2/L3).
template <int SPLIT>
__global__ __launch_bounds__(256, 2)
void k_gemm(const __bf16* __restrict__ A, const __bf16* __restrict__ Al,
            const __bf16* __restrict__ B, const __bf16* __restrict__ Bl,
            const float* __restrict__ bias, float* __restrict__ C,
            int M, int N, int Kt) {
  constexpr int BM = 128, BN = 128, BK = 64;
  __shared__ __align__(16) __bf16 sA[BM * BK];
  __shared__ __align__(16) __bf16 sB[BN * BK];
  __shared__ __align__(16) __bf16 sAl[SPLIT ? BM * BK : 8];
  __shared__ __align__(16) __bf16 sBl[SPLIT ? BN * BK : 8];

  const int tid = threadIdx.x;
  const int nbn = N / BN;
  int bm, bn;
  if ((M / BM) % 16 == 0 && nbn % 32 == 0) {  // supertile remap
    const int nsbn = nbn / 32;
    const int g = blockIdx.x >> 9, r = blockIdx.x & 511;
    bm = (g / nsbn) * 16 + (r >> 5);
    bn = (g % nsbn) * 32 + (r & 31);
  } else {
    bm = blockIdx.x / nbn;
    bn = blockIdx.x % nbn;
  }
  const int m0 = bm * BM, n0 = bn * BN;
  const int lane = tid & 63, wid = tid >> 6;
  const int wm = wid >> 1, wn = wid & 1;
  const int lr = lane & 15, lk = lane >> 4;
  const int swz = (lr & 7) << 4;

  f32x4 acc[4][4] = {};

  for (int k0 = 0; k0 < Kt; k0 += BK) {
#pragma unroll
    for (int r = 0; r < 4; ++r) {
      const int o = (r * 256 + tid) * 16;
      const int row = o >> 7;
      const int colb = (o & 127) ^ ((row & 7) << 4);
      const long gA = ((long)(m0 + row) * Kt + k0) * 2 + colb;
      const long gB = ((long)(n0 + row) * Kt + k0) * 2 + colb;
      gload_lds16((const char*)A + gA, (char*)sA + o);
      gload_lds16((const char*)B + gB, (char*)sB + o);
      if (SPLIT) {
        gload_lds16((const char*)Al + gA, (char*)sAl + o);
        gload_lds16((const char*)Bl + gB, (char*)sBl + o);
      }
    }
    __syncthreads();

#pragma unroll
    for (int kk = 0; kk < 2; ++kk) {
      bf16x8 va[4], vb[4], wa[4], wb[4];
      const int kbase = (kk * 64 + lk * 16) ^ swz;
#pragma unroll
      for (int m = 0; m < 4; ++m) {
        const int row = wm * 64 + m * 16 + lr;
        va[m] = *(const bf16x8*)((const char*)sA + row * 128 + kbase);
        if (SPLIT) wa[m] = *(const bf16x8*)((const char*)sAl + row * 128 + kbase);
      }
#pragma unroll
      for (int n = 0; n < 4; ++n) {
        const int row = wn * 64 + n * 16 + lr;
        vb[n] = *(const bf16x8*)((const char*)sB + row * 128 + kbase);
        if (SPLIT) wb[n] = *(const bf16x8*)((const char*)sBl + row * 128 + kbase);
      }
#pragma unroll
      for (int m = 0; m < 4; ++m)
#pragma unroll
        for (int n = 0; n < 4; ++n) {
          acc[m][n] = __builtin_amdgcn_mfma_f32_16x16x32_bf16(va[m], vb[n], acc[m][n], 0, 0, 0);
          if (SPLIT) {
            acc[m][n] = __builtin_amdgcn_mfma_f32_16x16x32_bf16(va[m], wb[n], acc[m][n], 0, 0, 0);
            acc[m][n] = __builtin_amdgcn_mfma_f32_16x16x32_bf16(wa[m], vb[n], acc[m][n], 0, 0, 0);
          }
        }
    }
    __syncthreads();
  }

#pragma unroll
  for (int n = 0; n < 4; ++n) {
    const int col = n0 + wn * 64 + n * 16 + lr;
    const float bv = bias[col];
#pragma unroll
    for (int m = 0; m < 4; ++m) {
      const int r0r = m0 + wm * 64 + m * 16 + lk * 4;
#pragma unroll
      for (int j = 0; j < 4; ++j)
        C[(long)(r0r + j) * N + col] = acc[m][n][j] + bv;
    }
  }
}

// ---------------- per-row k-th largest via 4-level radix select ----------------
__device__ __forceinline__ unsigned f2o(float f) {
  unsigned b = __float_as_uint(f);
  return ((int)b < 0) ? ~b : (b | 0x80000000u);
}
__device__ __forceinline__ float o2f(unsigned u) {
  unsigned b = (u & 0x80000000u) ? (u & 0x7FFFFFFFu) : ~u;
  return __uint_as_float(b);
}

__global__ void k_topk(const float* __restrict__ z1, float* __restrict__ thr,
                       int ncols, int kwant) {
  __shared__ unsigned hist[256];
  __shared__ unsigned s_dig, s_rem;
  const long base = (long)blockIdx.x * ncols;
  unsigned prefix = 0;
  unsigned remaining = (unsigned)kwant;
  for (int level = 0; level < 4; ++level) {
    const int shift = 24 - level * 8;
    hist[threadIdx.x] = 0;
    __syncthreads();
    const unsigned pmask = (level == 0) ? 0u : (0xFFFFFFFFu << (shift + 8));
    for (int i = threadIdx.x; i < ncols; i += 256) {
      unsigned u = f2o(z1[base + i]);
      if ((u & pmask) == (prefix & pmask))
        atomicAdd(&hist[(u >> shift) & 255u], 1u);
    }
    __syncthreads();
    if (threadIdx.x == 0) {
      unsigned cum = 0;
      int d = 255;
      for (; d > 0; --d) {
        if (cum + hist[d] >= remaining) break;
        cum += hist[d];
      }
      s_dig = (unsigned)d;
      s_rem = remaining - cum;
    }
    __syncthreads();
    prefix |= (s_dig << shift);
    remaining = s_rem;
    __syncthreads();
  }
  if (threadIdx.x == 0) thr[blockIdx.x] = o2f(prefix);
}

// ---------------- zero band scratch ----------------
__global__ void k_zero(f32x4* __restrict__ p, int nvec) {
  int i = blockIdx.x * 256 + threadIdx.x;
  const int stride = gridDim.x * 256;
  f32x4 z = {0.f, 0.f, 0.f, 0.f};
  for (; i < nvec; i += stride) p[i] = z;
}

// ---------------- band pass: per-row scan ----------------
__global__ void k_band(const float* __restrict__ z1, const float* __restrict__ thr,
                       unsigned* __restrict__ rowlist, unsigned* __restrict__ rowcnt,
                       unsigned* __restrict__ c1, unsigned* __restrict__ bucket,
                       unsigned* __restrict__ bcnt) {
  const int b = blockIdx.x;
  const float t = thr[b];
  const float hi = t + DELTA, lo = t - DELTA;
  __shared__ unsigned s_above, s_cnt;
  if (threadIdx.x == 0) { s_above = 0; s_cnt = 0; }
  __syncthreads();
  unsigned my_above = 0;
  const long base = (long)b * NROWS_W;
  for (int i = threadIdx.x; i < NROWS_W; i += 256) {
    const float v = z1[base + i];
    my_above += (v > hi) ? 1u : 0u;
    if (v >= lo && v <= hi) {
      unsigned j = atomicAdd(&s_cnt, 1u);
      if (j < ROWCAP) {
        rowlist[(long)b * ROWCAP + j] = (unsigned)i;
        unsigned p = atomicAdd(&bcnt[i], 1u);
        if (p < HCAP) bucket[(long)i * HCAP + p] = ((unsigned)b << 9) | j;
      }
    }
  }
  atomicAdd(&s_above, my_above);
  __syncthreads();
  if (threadIdx.x == 0) {
    rowcnt[b] = (s_cnt < ROWCAP) ? s_cnt : ROWCAP;
    c1[b] = s_above;
  }
}

// ---------------- h-major exact recompute ----------------
__global__ void k_recompute(const __bf16* __restrict__ Wh, const __bf16* __restrict__ Wl,
                            const __bf16* __restrict__ xh, const __bf16* __restrict__ xl,
                            const unsigned* __restrict__ bucket, const unsigned* __restrict__ bcnt,
                            float* __restrict__ exact) {
  const int h = blockIdx.x;
  unsigned n = bcnt[h];
  if (n > HCAP) n = HCAP;
  if (n == 0) return;
  __shared__ float wrec[DIM];  // 16 KB
  const long wb = (long)h * DIM;
  for (int i = threadIdx.x; i < DIM; i += 256)
    wrec[i] = (float)Wh[wb + i] + (float)Wl[wb + i];
  __syncthreads();
  const int w = threadIdx.x >> 6, lane = threadIdx.x & 63;
  for (unsigned e = w; e < n; e += 4) {
    const unsigned ent = bucket[(long)h * HCAP + e];
    const int b = ent >> 9, j = ent & 511;
    const bf16x8* ph = (const bf16x8*)(xh + (long)b * DIM);
    const bf16x8* pl = (const bf16x8*)(xl + (long)b * DIM);
    float s = 0.f;
#pragma unroll
    for (int c = 0; c < 8; ++c) {
      const int i8 = c * 64 + lane;
      bf16x8 vh = ph[i8], vl = pl[i8];
      const float* wr = &wrec[i8 * 8];
#pragma unroll
      for (int q = 0; q < 8; ++q) s += ((float)vh[q] + (float)vl[q]) * wr[q];
    }
#pragma unroll
    for (int m = 32; m; m >>= 1) s += __shfl_xor(s, m);
    if (lane == 0) exact[(long)b * ROWCAP + j] = s;
  }
}

// ---------------- per-row select top (k - C1) among band -> bitmap ----------------
__global__ void k_select(const float* __restrict__ exact, const unsigned* __restrict__ rowlist,
                         const unsigned* __restrict__ rowcnt, const unsigned* __restrict__ c1,
                         unsigned* __restrict__ bitmap) {
  const int b = blockIdx.x;
  const int n = (int)rowcnt[b];
  const int need = KCNT - (int)c1[b];
  __shared__ float vals[ROWCAP];
  for (int j = threadIdx.x; j < ROWCAP; j += 256)
    vals[j] = (j < n) ? exact[(long)b * ROWCAP + j] : -1e30f;
  __syncthreads();
  for (int j = threadIdx.x; j < ROWCAP; j += 256) {
    if (j >= n) continue;
    const float vj = vals[j];
    int rank = 0;
    for (int i = 0; i < n; ++i) {
      const float vi = vals[i];
      rank += (vi > vj || (vi == vj && i < j)) ? 1 : 0;
    }
    if (rank < need) {
      const unsigned h = rowlist[(long)b * ROWCAP + j];
      atomicOr(&bitmap[b * (NROWS_W / 32) + (h >> 5)], 1u << (h & 31));
    }
  }
}

// ---------------- apply mask, write bf16 a1 ----------------
__global__ void k_mask(const float* __restrict__ z1, const float* __restrict__ thr,
                       const unsigned* __restrict__ bitmap, __bf16* __restrict__ a1,
                       int n4, int ncols4) {
  int i = blockIdx.x * 256 + threadIdx.x;
  const int stride = gridDim.x * 256;
  for (; i < n4; i += stride) {
    f32x4 v = ((const f32x4*)z1)[i];
    const int row = i / ncols4;
    const int h0 = (i - row * ncols4) * 4;
    const float t = thr[row];
    const float hi = t + DELTA, lo = t - DELTA;
    const unsigned wbits = bitmap[row * (NROWS_W / 32) + (h0 >> 5)];
    bf16x4 o;
#pragma unroll
    for (int j = 0; j < 4; ++j) {
      const float vv = v[j];
      const bool sel = (vv > hi) || (vv >= lo && ((wbits >> ((h0 + j) & 31)) & 1u));
      o[j] = sel ? (__bf16)vv : (__bf16)0.0f;
    }
    ((bf16x4*)a1)[i] = o;
  }
}

extern "C" void kernel_launch(void* const* d_in, const int* in_sizes, int n_in,
                              void* d_out, int out_size, void* d_ws, size_t ws_size,
                              hipStream_t stream) {
  const float* x     = (const float*)d_in[0];
  const float* W     = (const float*)d_in[1];
  const float* b_enc = (const float*)d_in[2];
  const float* b_dec = (const float*)d_in[3];
  float* out = (float*)d_out;

  const long NW = (long)NROWS_W * DIM;    // 134217728
  const long NX = (long)BATCH * DIM;      // 16777216
  const long NZ = (long)BATCH * NROWS_W;  // 134217728

  char* ws = (char*)d_ws;
  __bf16* Wh = (__bf16*)ws;        // 2*NW bytes
  __bf16* Wl = Wh + NW;            // 2*NW
  char*   btr = (char*)(Wl + NW);  // 2*NW region: band scratch, later Wt
  __bf16* Wt = (__bf16*)btr;       // written by transpose AFTER band phase
  __bf16* xh = (__bf16*)(btr + 2 * NW);  // 2*NX
  __bf16* xl = xh + NX;            // 2*NX
  float*  z1 = (float*)(xl + NX);  // 4*NZ
  float*  thr = z1 + NZ;           // 4*BATCH
  __bf16* a1 = Wl;                 // Wl dead after recompute -> reuse as a1

  // band scratch layout inside btr (dead before transpose writes Wt):
  unsigned* rowcnt  = (unsigned*)(btr);                 // 16 KB
  unsigned* c1      = (unsigned*)(btr + 16384);         // 16 KB
  unsigned* bcnt    = (unsigned*)(btr + 32768);         // 128 KB
  unsigned* bitmap  = (unsigned*)(btr + 163840);        // 16 MB
  float*    exact   = (float*)(btr + 16941056);         // 6 MB
  const long ZERO_BYTES = 23232512;                     // rowcnt..exact
  unsigned* rowlist = (unsigned*)(btr + 23232512);      // 6 MB
  unsigned* bucket  = (unsigned*)(btr + 29523968);      // 8 MB (ends ~37.9 MB)

  const size_t needed = (size_t)(6 * NW + 4 * NX) + (size_t)4 * NZ + 4 * BATCH;
  if (ws_size < needed) return;

  k_split<<<2048, 256, 0, stream>>>(W, Wh, Wl, (int)(NW / 4));
  k_split<<<2048, 256, 0, stream>>>(x, xh, xl, (int)(NX / 4));

  // encoder (approx): z1 = xh @ Wh^T + b_enc
  k_gemm<0><<<(BATCH / 128) * (NROWS_W / 128), 256, 0, stream>>>(
      xh, nullptr, Wh, nullptr, b_enc, z1, BATCH, NROWS_W, DIM);

  k_topk<<<BATCH, 256, 0, stream>>>(z1, thr, NROWS_W, KCNT);

  k_zero<<<1024, 256, 0, stream>>>((f32x4*)btr, (int)(ZERO_BYTES / 16));
  k_band<<<BATCH, 256, 0, stream>>>(z1, thr, rowlist, rowcnt, c1, bucket, bcnt);
  k_recompute<<<NROWS_W, 256, 0, stream>>>(Wh, Wl, xh, xl, bucket, bcnt, exact);
  k_select<<<BATCH, 256, 0, stream>>>(exact, rowlist, rowcnt, c1, bitmap);
  k_mask<<<2048, 256, 0, stream>>>(z1, thr, bitmap, a1, (int)(NZ / 4), NROWS_W / 4);

  // band scratch dead; now build Wt and decode
  k_transpose<<<dim3(DIM / 32, NROWS_W / 32), dim3(32, 8), 0, stream>>>(Wh, Wt, NROWS_W, DIM);
  k_gemm<0><<<(BATCH / 128) * (DIM / 128), 256, 0, stream>>>(
      a1, nullptr, Wt, nullptr, b_dec, out, BATCH, DIM, NROWS_W);
}